// Round 6
// baseline (315.736 us; speedup 1.0000x reference)
//
#include <hip/hip_runtime.h>

#define B_SZ 16384
#define D_SZ 256
#define C_SZ 2000
#define C_PAD 2048
#define MARGIN_F 1.0f

typedef __bf16 bf16x8 __attribute__((ext_vector_type(8)));
typedef float floatx16 __attribute__((ext_vector_type(16)));

__device__ inline void gld_lds16(const void* g, void* l) {
  __builtin_amdgcn_global_load_lds(
      (const __attribute__((address_space(1))) void*)g,
      (__attribute__((address_space(3))) void*)l, 16, 0, 0);
}

// Frag-major layout for mfma_f32_32x32x16_bf16 (layouts verified R3):
//   chunk(tile32, ks, lane) -> 8 bf16 at base + ((tile*16 + ks)*64 + lane)*8
//   lane holds M[tile*32 + (lane&31)][ks*16 + (lane>>5)*8 + j], j=0..7
// predf: 512 rowtiles x 16 ks x 64.  sigf: 64 coltiles x 16 ks x 64.

// ---- sig (D x C) fp32 -> sigf frag-major bf16, zero-pad cols >= C ----
__global__ __launch_bounds__(256) void convert_sigf_kernel(
    const float* __restrict__ sig, __bf16* __restrict__ sigf) {
  int t = blockIdx.x * 256 + threadIdx.x;   // 65536 chunks
  int lane = t & 63;
  int ks = (t >> 6) & 15;
  int ctg = t >> 10;
  int col = ctg * 32 + (lane & 31);
  int kb = ks * 16 + (lane >> 5) * 8;
  bf16x8 o;
  if (col < C_SZ) {
#pragma unroll
    for (int j = 0; j < 8; j++) o[j] = (__bf16)sig[(size_t)(kb + j) * C_SZ + col];
  } else {
#pragma unroll
    for (int j = 0; j < 8; j++) o[j] = (__bf16)0.f;
  }
  *(bf16x8*)(sigf + (size_t)t * 8) = o;
}

// ---- pred (B x D) fp32 -> predf frag-major bf16 ----
__global__ __launch_bounds__(256) void convert_predf_kernel(
    const float* __restrict__ pred, __bf16* __restrict__ predf) {
  int t = blockIdx.x * 256 + threadIdx.x;   // 524288 chunks
  int lane = t & 63;
  int ks = (t >> 6) & 15;
  int rt = t >> 10;
  int row = rt * 32 + (lane & 31);
  int kb = ks * 16 + (lane >> 5) * 8;
  const float* src = pred + (size_t)row * D_SZ + kb;
  float4 v0 = *(const float4*)src;
  float4 v1 = *(const float4*)(src + 4);
  bf16x8 o;
  o[0] = (__bf16)v0.x; o[1] = (__bf16)v0.y; o[2] = (__bf16)v0.z; o[3] = (__bf16)v0.w;
  o[4] = (__bf16)v1.x; o[5] = (__bf16)v1.y; o[6] = (__bf16)v1.z; o[7] = (__bf16)v1.w;
  *(bf16x8*)(predf + (size_t)t * 8) = o;
}

// ---- gt (exact fp32) + label-hinge correction: one wave per row ----
// GEMM sums hinge over ALL cols<C (no label mask); this kernel subtracts
// max(1 + s_bf16[b,lbl] - gt[b], 0), with s_bf16 = dot of bf16-rounded
// inputs in fp32 (matches MFMA to fp32-reassociation noise, ~1e-4).
__global__ __launch_bounds__(256) void gt_kernel(
    const float* __restrict__ pred, const float* __restrict__ sig,
    const int* __restrict__ label, float* __restrict__ gt,
    float* __restrict__ out) {
  int row = (blockIdx.x * 256 + threadIdx.x) >> 6;
  int lane = threadIdx.x & 63;
  int lbl = label[row];
  float4 p = *(const float4*)(pred + (size_t)row * D_SZ + lane * 4);
  float pv[4] = {p.x, p.y, p.z, p.w};
  float sf = 0.f, sb = 0.f;
#pragma unroll
  for (int i = 0; i < 4; i++) {
    float s = sig[(size_t)(lane * 4 + i) * C_SZ + lbl];
    sf += pv[i] * s;
    sb += (float)(__bf16)pv[i] * (float)(__bf16)s;
  }
#pragma unroll
  for (int off = 32; off > 0; off >>= 1) {
    sf += __shfl_down(sf, off, 64);
    sb += __shfl_down(sb, off, 64);
  }
  if (lane == 0) {
    gt[row] = sf;
    atomicAdd(out, -fmaxf(MARGIN_F + sb - sf, 0.f));
  }
}

// ---- GEMM + hinge: B in LDS once (1 barrier), full-K A in registers ----
// block = 256 rows x 128 cols, 4 waves; wave = 64 rows (2 rowtiles) x 128.
// Each bfr ds_read feeds 2 MFMAs -> 64 FLOP/LDS-byte: MFMA-bound.
// XCD swizzle: bid&7 = XCD; all 16 colgroups of a row-superblock land on
// one XCD -> A slice (1 MB) + sigf (1 MB) L2-resident.
__global__ __launch_bounds__(256, 2) void mfma_fused_kernel(
    const __bf16* __restrict__ predf, const __bf16* __restrict__ sigf,
    const float* __restrict__ gt, float* __restrict__ out) {
  __shared__ __bf16 Bs[4096 * 8];   // 64 KB
  __shared__ float red[4];
  int tid = threadIdx.x;
  int lane = tid & 63;
  int w = tid >> 6;
  int kh = lane >> 5, lm = lane & 31;
  int bid = (int)blockIdx.x;
  int i = bid >> 3;
  int rsb = (bid & 7) * 8 + (i & 7);   // row superblock 0..63 (256 rows)
  int cg = i >> 3;                     // colgroup 0..15 (128 cols)

  // stage B tile (128 cols x 256 K = 64 KB), straight frag-major copy
#pragma unroll
  for (int s = 0; s < 16; s++) {
    int q0 = s * 256 + w * 64;
    gld_lds16(sigf + ((size_t)cg * 4096 + q0 + lane) * 8, (void*)(Bs + (size_t)q0 * 8));
  }

  // A frags: full K for 2 rowtiles (rows rsb*256 + w*64 .. +63)
  bf16x8 afr[2][16];
#pragma unroll
  for (int rt = 0; rt < 2; rt++)
#pragma unroll
    for (int ks = 0; ks < 16; ks++)
      afr[rt][ks] = *(const bf16x8*)(predf +
          (((size_t)(rsb * 8 + w * 2 + rt) * 16 + ks) * 64 + lane) * 8);

  // mg = margin - gt for the rows this lane owns (C/D row map, verified R3)
  float mgv[2][16];
#pragma unroll
  for (int rt = 0; rt < 2; rt++)
#pragma unroll
    for (int reg = 0; reg < 16; reg++) {
      int row = rsb * 256 + w * 64 + rt * 32 + (reg & 3) + 8 * (reg >> 2) + 4 * kh;
      mgv[rt][reg] = MARGIN_F - gt[row];
    }
  __syncthreads();

  float sum = 0.f;
  for (int ct = 0; ct < 4; ct++) {
    floatx16 acc0 = {}, acc1 = {};
#pragma unroll
    for (int ks = 0; ks < 16; ks++) {
      bf16x8 bfr = *(const bf16x8*)(Bs + (size_t)((ct * 16 + ks) * 64 + lane) * 8);
      acc0 = __builtin_amdgcn_mfma_f32_32x32x16_bf16(afr[0][ks], bfr, acc0, 0, 0, 0);
      acc1 = __builtin_amdgcn_mfma_f32_32x32x16_bf16(afr[1][ks], bfr, acc1, 0, 0, 0);
    }
    int col = cg * 128 + ct * 32 + lm;
    float keep = (col < C_SZ) ? 1.f : 0.f;
#pragma unroll
    for (int reg = 0; reg < 16; reg++) {
      sum += keep * fmaxf(acc0[reg] + mgv[0][reg], 0.f);
      sum += keep * fmaxf(acc1[reg] + mgv[1][reg], 0.f);
    }
  }
#pragma unroll
  for (int off = 32; off > 0; off >>= 1) sum += __shfl_down(sum, off, 64);
  if (lane == 0) red[w] = sum;
  __syncthreads();
  if (tid == 0) atomicAdd(out, red[0] + red[1] + red[2] + red[3]);
}

extern "C" void kernel_launch(void* const* d_in, const int* in_sizes, int n_in,
                              void* d_out, int out_size, void* d_ws, size_t ws_size,
                              hipStream_t stream) {
  const float* pred  = (const float*)d_in[0];   // (B, D) fp32
  const int*   label = (const int*)d_in[1];     // (B,)
  // d_in[2] = train_classes = arange(C), unused
  const float* sig   = (const float*)d_in[3];   // (D, C) fp32
  float* out = (float*)d_out;

  float*  gt    = (float*)d_ws;                                   // 64 KB
  __bf16* predf = (__bf16*)((char*)d_ws + (64 << 10));            // 8 MB
  __bf16* sigf  = (__bf16*)((char*)d_ws + (64 << 10) + (8 << 20));// 1 MB

  hipMemsetAsync(out, 0, sizeof(float), stream);
  convert_sigf_kernel<<<256, 256, 0, stream>>>(sig, sigf);
  convert_predf_kernel<<<2048, 256, 0, stream>>>(pred, predf);
  gt_kernel<<<B_SZ / 4, 256, 0, stream>>>(pred, sig, label, gt, out);
  mfma_fused_kernel<<<64 * 16, 256, 0, stream>>>(predf, sigf, gt, out);
}

// Round 7
// 118.152 us; speedup vs baseline: 2.6723x; 2.6723x over previous
//
#include <hip/hip_runtime.h>

#define B_SZ 16384
#define D_SZ 256
#define C_SZ 2000
#define C_PAD 2048
#define MARGIN_F 1.0f
#define NBLK 1024

typedef __bf16 bf16x8 __attribute__((ext_vector_type(8)));
typedef float floatx16 __attribute__((ext_vector_type(16)));

__device__ inline void gld_lds16(const void* g, void* l) {
  __builtin_amdgcn_global_load_lds(
      (const __attribute__((address_space(1))) void*)g,
      (__attribute__((address_space(3))) void*)l, 16, 0, 0);
}

// Frag-major layout for mfma_f32_32x32x16_bf16 (verified R3):
//   chunk(tile32, ks, lane) -> 8 bf16 at base + ((tile*16 + ks)*64 + lane)*8
//   lane holds M[tile*32 + (lane&31)][ks*16 + (lane>>5)*8 + j], j=0..7

// ---- sig (D x C) fp32 -> sigf frag-major bf16, zero-pad cols >= C ----
__global__ __launch_bounds__(256) void convert_sigf_kernel(
    const float* __restrict__ sig, __bf16* __restrict__ sigf) {
  int t = blockIdx.x * 256 + threadIdx.x;   // 65536 chunks
  int lane = t & 63;
  int ks = (t >> 6) & 15;
  int ctg = t >> 10;
  int col = ctg * 32 + (lane & 31);
  int kb = ks * 16 + (lane >> 5) * 8;
  bf16x8 o;
  if (col < C_SZ) {
#pragma unroll
    for (int j = 0; j < 8; j++) o[j] = (__bf16)sig[(size_t)(kb + j) * C_SZ + col];
  } else {
#pragma unroll
    for (int j = 0; j < 8; j++) o[j] = (__bf16)0.f;
  }
  *(bf16x8*)(sigf + (size_t)t * 8) = o;
}

// ---- pred (B x D) fp32 -> predf frag-major bf16 ----
__global__ __launch_bounds__(256) void convert_predf_kernel(
    const float* __restrict__ pred, __bf16* __restrict__ predf) {
  int t = blockIdx.x * 256 + threadIdx.x;   // 524288 chunks
  int lane = t & 63;
  int ks = (t >> 6) & 15;
  int rt = t >> 10;
  int row = rt * 32 + (lane & 31);
  int kb = ks * 16 + (lane >> 5) * 8;
  const float* src = pred + (size_t)row * D_SZ + kb;
  float4 v0 = *(const float4*)src;
  float4 v1 = *(const float4*)(src + 4);
  bf16x8 o;
  o[0] = (__bf16)v0.x; o[1] = (__bf16)v0.y; o[2] = (__bf16)v0.z; o[3] = (__bf16)v0.w;
  o[4] = (__bf16)v1.x; o[5] = (__bf16)v1.y; o[6] = (__bf16)v1.z; o[7] = (__bf16)v1.w;
  *(bf16x8*)(predf + (size_t)t * 8) = o;
}

// ---- gt (exact fp32) + label-hinge correction per row; NO atomics ----
// GEMM sums hinge over all cols<C (no label mask); corr[row] holds the
// label column's hinge computed from bf16-rounded inputs in fp32
// (matches MFMA to reassociation noise ~1e-4; subtracted in reduce).
__global__ __launch_bounds__(256) void gt_kernel(
    const float* __restrict__ pred, const float* __restrict__ sig,
    const int* __restrict__ label, float* __restrict__ gt,
    float* __restrict__ corr) {
  int row = (blockIdx.x * 256 + threadIdx.x) >> 6;
  int lane = threadIdx.x & 63;
  int lbl = label[row];
  float4 p = *(const float4*)(pred + (size_t)row * D_SZ + lane * 4);
  float pv[4] = {p.x, p.y, p.z, p.w};
  float sf = 0.f, sb = 0.f;
#pragma unroll
  for (int i = 0; i < 4; i++) {
    float s = sig[(size_t)(lane * 4 + i) * C_SZ + lbl];
    sf += pv[i] * s;
    sb += (float)(__bf16)pv[i] * (float)(__bf16)s;
  }
#pragma unroll
  for (int off = 32; off > 0; off >>= 1) {
    sf += __shfl_down(sf, off, 64);
    sb += __shfl_down(sb, off, 64);
  }
  if (lane == 0) {
    gt[row] = sf;
    corr[row] = fmaxf(MARGIN_F + sb - sf, 0.f);
  }
}

// ---- GEMM + hinge: B in LDS once (1 barrier), full-K A in registers ----
// block = 256 rows x 128 cols, 4 waves; wave = 64 rows (2 rowtiles) x 128.
// Each bfr ds_read feeds 2 MFMAs -> 64 FLOP/LDS-byte: MFMA-bound.
// Partial sum written to partial[bid]; no atomics.
__global__ __launch_bounds__(256, 2) void mfma_fused_kernel(
    const __bf16* __restrict__ predf, const __bf16* __restrict__ sigf,
    const float* __restrict__ gt, float* __restrict__ partial) {
  __shared__ __bf16 Bs[4096 * 8];   // 64 KB
  __shared__ float red[4];
  int tid = threadIdx.x;
  int lane = tid & 63;
  int w = tid >> 6;
  int kh = lane >> 5, lm = lane & 31;
  int bid = (int)blockIdx.x;
  int i = bid >> 3;
  int rsb = (bid & 7) * 8 + (i & 7);   // row superblock 0..63 (256 rows)
  int cg = i >> 3;                     // colgroup 0..15 (128 cols)

  // stage B tile (128 cols x 256 K = 64 KB), straight frag-major copy
#pragma unroll
  for (int s = 0; s < 16; s++) {
    int q0 = s * 256 + w * 64;
    gld_lds16(sigf + ((size_t)cg * 4096 + q0 + lane) * 8, (void*)(Bs + (size_t)q0 * 8));
  }

  // A frags: full K for 2 rowtiles (rows rsb*256 + w*64 .. +63)
  bf16x8 afr[2][16];
#pragma unroll
  for (int rt = 0; rt < 2; rt++)
#pragma unroll
    for (int ks = 0; ks < 16; ks++)
      afr[rt][ks] = *(const bf16x8*)(predf +
          (((size_t)(rsb * 8 + w * 2 + rt) * 16 + ks) * 64 + lane) * 8);

  // mg = margin - gt for the rows this lane owns (C/D row map, verified R3)
  float mgv[2][16];
#pragma unroll
  for (int rt = 0; rt < 2; rt++)
#pragma unroll
    for (int reg = 0; reg < 16; reg++) {
      int row = rsb * 256 + w * 64 + rt * 32 + (reg & 3) + 8 * (reg >> 2) + 4 * kh;
      mgv[rt][reg] = MARGIN_F - gt[row];
    }
  __syncthreads();

  float sum = 0.f;
  for (int ct = 0; ct < 4; ct++) {
    floatx16 acc0 = {}, acc1 = {};
#pragma unroll
    for (int ks = 0; ks < 16; ks++) {
      bf16x8 bfr = *(const bf16x8*)(Bs + (size_t)((ct * 16 + ks) * 64 + lane) * 8);
      acc0 = __builtin_amdgcn_mfma_f32_32x32x16_bf16(afr[0][ks], bfr, acc0, 0, 0, 0);
      acc1 = __builtin_amdgcn_mfma_f32_32x32x16_bf16(afr[1][ks], bfr, acc1, 0, 0, 0);
    }
    int col = cg * 128 + ct * 32 + lm;
    float keep = (col < C_SZ) ? 1.f : 0.f;
#pragma unroll
    for (int reg = 0; reg < 16; reg++) {
      sum += keep * fmaxf(acc0[reg] + mgv[0][reg], 0.f);
      sum += keep * fmaxf(acc1[reg] + mgv[1][reg], 0.f);
    }
  }
#pragma unroll
  for (int off = 32; off > 0; off >>= 1) sum += __shfl_down(sum, off, 64);
  if (lane == 0) red[w] = sum;
  __syncthreads();
  if (tid == 0) partial[bid] = red[0] + red[1] + red[2] + red[3];
}

// ---- final reduce: out = sum(partial) - sum(corr); single block ----
__global__ __launch_bounds__(256) void reduce_kernel(
    const float* __restrict__ partial, const float* __restrict__ corr,
    float* __restrict__ out) {
  int tid = threadIdx.x;
  float s = 0.f;
  for (int i = tid; i < NBLK; i += 256) s += partial[i];
  for (int i = tid * 4; i < B_SZ; i += 1024) {
    float4 c = *(const float4*)(corr + i);
    s -= c.x + c.y + c.z + c.w;
  }
#pragma unroll
  for (int off = 32; off > 0; off >>= 1) s += __shfl_down(s, off, 64);
  __shared__ float red[4];
  if ((tid & 63) == 0) red[tid >> 6] = s;
  __syncthreads();
  if (tid == 0) out[0] = red[0] + red[1] + red[2] + red[3];
}

extern "C" void kernel_launch(void* const* d_in, const int* in_sizes, int n_in,
                              void* d_out, int out_size, void* d_ws, size_t ws_size,
                              hipStream_t stream) {
  const float* pred  = (const float*)d_in[0];   // (B, D) fp32
  const int*   label = (const int*)d_in[1];     // (B,)
  // d_in[2] = train_classes = arange(C), unused
  const float* sig   = (const float*)d_in[3];   // (D, C) fp32
  float* out = (float*)d_out;

  float*  gt      = (float*)d_ws;                                  // 64 KB
  float*  corr    = (float*)((char*)d_ws + (64 << 10));            // 64 KB
  float*  partial = (float*)((char*)d_ws + (128 << 10));           // 4 KB
  __bf16* predf   = (__bf16*)((char*)d_ws + (192 << 10));          // 8 MB
  __bf16* sigf    = (__bf16*)((char*)d_ws + (192 << 10) + (8 << 20)); // 1 MB

  convert_sigf_kernel<<<256, 256, 0, stream>>>(sig, sigf);
  convert_predf_kernel<<<2048, 256, 0, stream>>>(pred, predf);
  gt_kernel<<<B_SZ / 4, 256, 0, stream>>>(pred, sig, label, gt, corr);
  mfma_fused_kernel<<<NBLK, 256, 0, stream>>>(predf, sigf, gt, partial);
  reduce_kernel<<<1, 256, 0, stream>>>(partial, corr, out);
}

// Round 8
// 111.741 us; speedup vs baseline: 2.8256x; 1.0574x over previous
//
#include <hip/hip_runtime.h>

#define B_SZ 16384
#define D_SZ 256
#define C_SZ 2000
#define C_PAD 2048
#define MARGIN_F 1.0f
#define NBLK 1024

typedef __bf16 bf16x8 __attribute__((ext_vector_type(8)));
typedef float floatx16 __attribute__((ext_vector_type(16)));

__device__ inline void gld_lds16(const void* g, void* l) {
  __builtin_amdgcn_global_load_lds(
      (const __attribute__((address_space(1))) void*)g,
      (__attribute__((address_space(3))) void*)l, 16, 0, 0);
}

// Frag-major layout for mfma_f32_32x32x16_bf16 (verified R3/R6/R7):
//   chunk(tile32, ks, lane) -> 8 bf16 at base + ((tile*16 + ks)*64 + lane)*8
//   lane holds M[tile*32 + (lane&31)][ks*16 + (lane>>5)*8 + j], j=0..7

// ---- fused prep ----
// blocks 0..511:  rowtile r=bid (32 rows): pred -> LDS (1 coalesced read),
//                 then (a) frag-major predf (coalesced 1KB writes),
//                 (b) gt (exact fp32) + corr (label-hinge on bf16-rounded
//                 inputs; GEMM skips the label mask, reduce subtracts corr).
// blocks 512..575: sigf frag-major conversion (gathers hide under pred stream)
__global__ __launch_bounds__(256) void prep_kernel(
    const float* __restrict__ pred, const float* __restrict__ sig,
    const int* __restrict__ label, __bf16* __restrict__ predf,
    __bf16* __restrict__ sigf, float* __restrict__ gt,
    float* __restrict__ corr) {
  int bid = (int)blockIdx.x;
  int tid = threadIdx.x;
  if (bid < 512) {
    __shared__ float ldsP[32][257];   // +1 pad: conflict-free everywhere
    // phase A: coalesced tile load (32 rows x 256 cols fp32)
#pragma unroll
    for (int it = 0; it < 8; it++) {
      int idx = it * 1024 + tid * 4;
      int r = idx >> 8, c = idx & 255;
      float4 v = *(const float4*)(pred + (size_t)(bid * 32 + r) * D_SZ + c);
      ldsP[r][c] = v.x; ldsP[r][c + 1] = v.y;
      ldsP[r][c + 2] = v.z; ldsP[r][c + 3] = v.w;
    }
    __syncthreads();
    // phase B: frag-major predf, coalesced writes (lane fastest)
#pragma unroll
    for (int it = 0; it < 4; it++) {
      int ch = it * 256 + tid;          // 0..1023
      int lane = ch & 63, ks = ch >> 6; // ks 0..15
      int r = lane & 31, kb = ks * 16 + (lane >> 5) * 8;
      bf16x8 o;
#pragma unroll
      for (int j = 0; j < 8; j++) o[j] = (__bf16)ldsP[r][kb + j];
      *(bf16x8*)(predf + ((size_t)(bid * 16 + ks) * 64 + lane) * 8) = o;
    }
    // phase C: gt + corr; 4 waves x 8 rows
    int lane = tid & 63, w = tid >> 6;
    for (int rr = 0; rr < 8; rr++) {
      int r = w * 8 + rr;
      int row = bid * 32 + r;
      int lbl = label[row];
      float sf = 0.f, sb = 0.f;
#pragma unroll
      for (int i = 0; i < 4; i++) {
        float p = ldsP[r][lane * 4 + i];
        float s = sig[(size_t)(lane * 4 + i) * C_SZ + lbl];
        sf += p * s;
        sb += (float)(__bf16)p * (float)(__bf16)s;
      }
#pragma unroll
      for (int off = 32; off > 0; off >>= 1) {
        sf += __shfl_down(sf, off, 64);
        sb += __shfl_down(sb, off, 64);
      }
      if (lane == 0) {
        gt[row] = sf;
        corr[row] = fmaxf(MARGIN_F + sb - sf, 0.f);
      }
    }
  } else {
    int ct = bid - 512;                 // coltile 0..63
#pragma unroll
    for (int it = 0; it < 4; it++) {
      int ch = it * 256 + tid;
      int lane = ch & 63, ks = ch >> 6;
      int col = ct * 32 + (lane & 31);
      int kb = ks * 16 + (lane >> 5) * 8;
      bf16x8 o;
      if (col < C_SZ) {
#pragma unroll
        for (int j = 0; j < 8; j++) o[j] = (__bf16)sig[(size_t)(kb + j) * C_SZ + col];
      } else {
#pragma unroll
        for (int j = 0; j < 8; j++) o[j] = (__bf16)0.f;
      }
      *(bf16x8*)(sigf + ((size_t)(ct * 16 + ks) * 64 + lane) * 8) = o;
    }
  }
}

// ---- GEMM + hinge: B in LDS once (1 barrier), full-K A in registers ----
// block = 256 rows x 128 cols, 4 waves; wave = 64 rows (2 rowtiles) x 128.
// Each bfr ds_read feeds 2 MFMAs -> 64 FLOP/LDS-byte: MFMA/LDS balanced.
__global__ __launch_bounds__(256, 2) void mfma_fused_kernel(
    const __bf16* __restrict__ predf, const __bf16* __restrict__ sigf,
    const float* __restrict__ gt, float* __restrict__ partial) {
  __shared__ __bf16 Bs[4096 * 8];   // 64 KB
  __shared__ float red[4];
  int tid = threadIdx.x;
  int lane = tid & 63;
  int w = tid >> 6;
  int kh = lane >> 5, lm = lane & 31;
  int bid = (int)blockIdx.x;
  int i = bid >> 3;
  int rsb = (bid & 7) * 8 + (i & 7);   // row superblock 0..63 (256 rows)
  int cg = i >> 3;                     // colgroup 0..15 (128 cols)

  // stage B tile (128 cols x 256 K = 64 KB), straight frag-major copy
#pragma unroll
  for (int s = 0; s < 16; s++) {
    int q0 = s * 256 + w * 64;
    gld_lds16(sigf + ((size_t)cg * 4096 + q0 + lane) * 8, (void*)(Bs + (size_t)q0 * 8));
  }

  // A frags: full K for 2 rowtiles (rows rsb*256 + w*64 .. +63)
  bf16x8 afr[2][16];
#pragma unroll
  for (int rt = 0; rt < 2; rt++)
#pragma unroll
    for (int ks = 0; ks < 16; ks++)
      afr[rt][ks] = *(const bf16x8*)(predf +
          (((size_t)(rsb * 8 + w * 2 + rt) * 16 + ks) * 64 + lane) * 8);

  // mg = margin - gt for the rows this lane owns (C/D row map, verified R3)
  float mgv[2][16];
#pragma unroll
  for (int rt = 0; rt < 2; rt++)
#pragma unroll
    for (int reg = 0; reg < 16; reg++) {
      int row = rsb * 256 + w * 64 + rt * 32 + (reg & 3) + 8 * (reg >> 2) + 4 * kh;
      mgv[rt][reg] = MARGIN_F - gt[row];
    }
  __syncthreads();

  float sum = 0.f;
  for (int ct = 0; ct < 4; ct++) {
    floatx16 acc0 = {}, acc1 = {};
#pragma unroll
    for (int ks = 0; ks < 16; ks++) {
      bf16x8 bfr = *(const bf16x8*)(Bs + (size_t)((ct * 16 + ks) * 64 + lane) * 8);
      acc0 = __builtin_amdgcn_mfma_f32_32x32x16_bf16(afr[0][ks], bfr, acc0, 0, 0, 0);
      acc1 = __builtin_amdgcn_mfma_f32_32x32x16_bf16(afr[1][ks], bfr, acc1, 0, 0, 0);
    }
    int col = cg * 128 + ct * 32 + lm;
    float keep = (col < C_SZ) ? 1.f : 0.f;
#pragma unroll
    for (int reg = 0; reg < 16; reg++) {
      sum += keep * fmaxf(acc0[reg] + mgv[0][reg], 0.f);
      sum += keep * fmaxf(acc1[reg] + mgv[1][reg], 0.f);
    }
  }
#pragma unroll
  for (int off = 32; off > 0; off >>= 1) sum += __shfl_down(sum, off, 64);
  if (lane == 0) red[w] = sum;
  __syncthreads();
  if (tid == 0) partial[bid] = red[0] + red[1] + red[2] + red[3];
}

// ---- final reduce: out = sum(partial) - sum(corr); single block ----
__global__ __launch_bounds__(256) void reduce_kernel(
    const float* __restrict__ partial, const float* __restrict__ corr,
    float* __restrict__ out) {
  int tid = threadIdx.x;
  float s = 0.f;
  for (int i = tid; i < NBLK; i += 256) s += partial[i];
  for (int i = tid * 4; i < B_SZ; i += 1024) {
    float4 c = *(const float4*)(corr + i);
    s -= c.x + c.y + c.z + c.w;
  }
#pragma unroll
  for (int off = 32; off > 0; off >>= 1) s += __shfl_down(s, off, 64);
  __shared__ float red[4];
  if ((tid & 63) == 0) red[tid >> 6] = s;
  __syncthreads();
  if (tid == 0) out[0] = red[0] + red[1] + red[2] + red[3];
}

extern "C" void kernel_launch(void* const* d_in, const int* in_sizes, int n_in,
                              void* d_out, int out_size, void* d_ws, size_t ws_size,
                              hipStream_t stream) {
  const float* pred  = (const float*)d_in[0];   // (B, D) fp32
  const int*   label = (const int*)d_in[1];     // (B,)
  // d_in[2] = train_classes = arange(C), unused
  const float* sig   = (const float*)d_in[3];   // (D, C) fp32
  float* out = (float*)d_out;

  float*  gt      = (float*)d_ws;                                  // 64 KB
  float*  corr    = (float*)((char*)d_ws + (64 << 10));            // 64 KB
  float*  partial = (float*)((char*)d_ws + (128 << 10));           // 4 KB
  __bf16* predf   = (__bf16*)((char*)d_ws + (192 << 10));          // 8 MB
  __bf16* sigf    = (__bf16*)((char*)d_ws + (192 << 10) + (8 << 20)); // 1 MB

  prep_kernel<<<576, 256, 0, stream>>>(pred, sig, label, predf, sigf, gt, corr);
  mfma_fused_kernel<<<NBLK, 256, 0, stream>>>(predf, sigf, gt, partial);
  reduce_kernel<<<1, 256, 0, stream>>>(partial, corr, out);
}